// Round 1
// 285.287 us; speedup vs baseline: 1.0215x; 1.0215x over previous
//
#include <hip/hip_runtime.h>
#include <math.h>

// Sparsemax along axis 0 of z = -exp(a)*x, x: (4096, 8192) f32 row-major.
// 8192 independent simplex projections over columns.
//
// R4: register-residency fix + wave-parallel Michelot.
// rocprof R3 evidence: VGPR_Count=64 while z needs 64 floats live across three
// phases, with zero scratch traffic => compiler was rematerializing z by
// RE-LOADING x from global (L3-served, invisible in FETCH_SIZE) for the filter
// scan and the epilogue: ~512 MiB moved instead of 256 MiB, each re-read pass
// re-paying full latency behind block barriers.
// Fixes:
//   1) asm volatile("" : "+v"(z...)) pins z in VGPRs after the load: the value
//      is now defined by the asm, so the backend cannot re-derive it from
//      memory. ~100 VGPRs -> 4 waves/EU (the floor anyway for a 16-wave block).
//   2) Michelot on the candidate list is now one WAVE per column (shfl_xor
//      reduction) instead of 1 thread per column serial -- with only 1 block/CU
//      resident there is no co-resident block to hide a serial phase.
//
// Mapping (unchanged): 1 block = 1024 threads = 16 columns; cq = tid&3 picks a
// 16B column quad, rg = tid>>2 the row group; each thread holds 16 rows x
// 4 cols = 64 f32; 4 lanes cover a full 64B line.

constexpr int ROWS = 4096;
constexpr int COLS = 8192;
constexpr int TPB  = 1024;
constexpr int CPB  = 16;
constexpr int RPT  = 16;
constexpr int WPB  = TPB / 64;      // 16 waves = 16 columns for the solve
constexpr int CAP  = 64;            // candidate capacity per column (1/lane)
constexpr int MSTR = 20;            // max-reduce LDS row stride (floats)
constexpr int FSTR = 36;            // fallback reduce LDS row stride

__global__ __launch_bounds__(TPB, 4)
void sparsemax_cols(const float* __restrict__ x, const float* __restrict__ a,
                    float* __restrict__ out)
{
    __shared__ float red[WPB * MSTR];    // per-wave column maxima [wave][cq*4+c]
    __shared__ float m_col[CPB];         // column maxima
    __shared__ float cand[CPB][CAP];     // candidate values per column
    __shared__ int   cnt[CPB];           // candidate counts
    __shared__ int   overflow;           // any column over capacity?
    __shared__ float tauLDS[CPB];        // solved tau per column
    __shared__ float fred[WPB * FSTR];   // fallback: per-wave (sum,count) partials
    __shared__ float ffin[32];           // fallback: block totals

    const int tid  = threadIdx.x;
    const int cq   = tid & 3;
    const int rg   = tid >> 2;
    const int lane = tid & 63;
    const int wave = tid >> 6;

    if (tid < CPB) cnt[tid] = 0;
    if (tid == 0)  overflow = 0;

    const long col = (long)blockIdx.x * CPB + cq * 4;
    const float s  = -expf(a[0]);

    // ---- load z = s*x: 16 rows x 4 cols per thread ----
    float z[RPT][4];
    #pragma unroll
    for (int k = 0; k < RPT; ++k) {
        const long row = rg + k * 256;
        const float4 v = *reinterpret_cast<const float4*>(x + row * COLS + col);
        z[k][0] = s * v.x; z[k][1] = s * v.y;
        z[k][2] = s * v.z; z[k][3] = s * v.w;
    }
    // Pin z in VGPRs: each value is now defined by an opaque asm op, so the
    // compiler cannot rematerialize it via a global re-load in later phases.
    #pragma unroll
    for (int k = 0; k < RPT; ++k) {
        asm volatile("" : "+v"(z[k][0]), "+v"(z[k][1]),
                          "+v"(z[k][2]), "+v"(z[k][3]));
    }

    // ---- per-column max: thread-local -> wave butterfly -> cross-wave ----
    float pm[4] = {z[0][0], z[0][1], z[0][2], z[0][3]};
    #pragma unroll
    for (int k = 1; k < RPT; ++k) {
        #pragma unroll
        for (int c = 0; c < 4; ++c) pm[c] = fmaxf(pm[c], z[k][c]);
    }
    #pragma unroll
    for (int m = 4; m < 64; m <<= 1) {   // cq-preserving masks
        #pragma unroll
        for (int c = 0; c < 4; ++c) pm[c] = fmaxf(pm[c], __shfl_xor(pm[c], m, 64));
    }
    if (lane < 4) {                      // lane == cq
        #pragma unroll
        for (int c = 0; c < 4; ++c) red[wave * MSTR + lane * 4 + c] = pm[c];
    }
    __syncthreads();
    if (tid < CPB) {
        float m = red[tid];
        #pragma unroll
        for (int w = 1; w < WPB; ++w) m = fmaxf(m, red[w * MSTR + tid]);
        m_col[tid] = m;
    }
    __syncthreads();

    // ---- filter scan (from registers): append z > colmax - 1 to LDS lists ----
    float thr[4];
    #pragma unroll
    for (int c = 0; c < 4; ++c) thr[c] = m_col[cq * 4 + c] - 1.0f;
    #pragma unroll
    for (int k = 0; k < RPT; ++k) {
        #pragma unroll
        for (int c = 0; c < 4; ++c) {
            const float v = z[k][c];
            if (v > thr[c]) {
                const int ci  = cq * 4 + c;
                const int idx = atomicAdd(&cnt[ci], 1);
                if (idx < CAP) cand[ci][idx] = v;
                else           overflow = 1;
            }
        }
    }
    __syncthreads();

    float tau[4];
    if (!overflow) {
        // ---- wave-parallel Michelot: wave w solves column w ----
        const int K = min(cnt[wave], CAP);
        const float v = (lane < K) ? cand[wave][lane] : -3.3e38f;
        float t = -3.0e38f, prev = 0.f;
        for (int it = 0; it < CAP + 2; ++it) {
            const bool act = v > t;
            float ssum = act ? v : 0.f;
            float scnt = act ? 1.f : 0.f;
            #pragma unroll
            for (int m = 1; m < 64; m <<= 1) {
                ssum += __shfl_xor(ssum, m, 64);
                scnt += __shfl_xor(scnt, m, 64);
            }
            t = (ssum - 1.0f) / scnt;     // scnt >= 1 (max always in support)
            if (scnt == prev) break;      // wave-uniform: scnt is fully reduced
            prev = scnt;
        }
        if (lane == 0) tauLDS[wave] = t;
        __syncthreads();
        #pragma unroll
        for (int c = 0; c < 4; ++c) tau[c] = tauLDS[cq * 4 + c];
    } else {
        // ---- fallback: exact block-wide Michelot over all 16 columns ----
        float t4[4]    = {-1e30f, -1e30f, -1e30f, -1e30f};
        float prevc[4] = {-1.f, -1.f, -1.f, -1.f};
        for (int it = 0; it < 80; ++it) {
            float ps[4] = {0.f, 0.f, 0.f, 0.f};
            float pc[4] = {0.f, 0.f, 0.f, 0.f};
            #pragma unroll
            for (int k = 0; k < RPT; ++k) {
                #pragma unroll
                for (int c = 0; c < 4; ++c) {
                    if (z[k][c] > t4[c]) { ps[c] += z[k][c]; pc[c] += 1.f; }
                }
            }
            #pragma unroll
            for (int m = 4; m < 64; m <<= 1) {
                #pragma unroll
                for (int c = 0; c < 4; ++c) {
                    ps[c] += __shfl_xor(ps[c], m, 64);
                    pc[c] += __shfl_xor(pc[c], m, 64);
                }
            }
            if (lane < 4) {
                float* dst = fred + wave * FSTR + lane * 8;
                *reinterpret_cast<float4*>(dst)     = make_float4(ps[0], ps[1], ps[2], ps[3]);
                *reinterpret_cast<float4*>(dst + 4) = make_float4(pc[0], pc[1], pc[2], pc[3]);
            }
            __syncthreads();
            if (tid < 32) {
                float t = 0.f;
                #pragma unroll
                for (int w = 0; w < WPB; ++w) t += fred[w * FSTR + tid];
                ffin[tid] = t;
            }
            __syncthreads();
            const float4 ts = *reinterpret_cast<const float4*>(ffin + cq * 8);
            const float4 tc = *reinterpret_cast<const float4*>(ffin + cq * 8 + 4);
            t4[0] = (ts.x - 1.0f) / tc.x;
            t4[1] = (ts.y - 1.0f) / tc.y;
            t4[2] = (ts.z - 1.0f) / tc.z;
            t4[3] = (ts.w - 1.0f) / tc.w;
            int done = (tc.x == prevc[0]) & (tc.y == prevc[1]) &
                       (tc.z == prevc[2]) & (tc.w == prevc[3]);
            prevc[0] = tc.x; prevc[1] = tc.y; prevc[2] = tc.z; prevc[3] = tc.w;
            if (__syncthreads_and(done)) break;
        }
        #pragma unroll
        for (int c = 0; c < 4; ++c) tau[c] = t4[c];
    }

    // ---- epilogue: out = max(z - tau, 0), full-line float4 stores ----
    #pragma unroll
    for (int k = 0; k < RPT; ++k) {
        const long row = rg + k * 256;
        float4 o;
        o.x = fmaxf(z[k][0] - tau[0], 0.f);
        o.y = fmaxf(z[k][1] - tau[1], 0.f);
        o.z = fmaxf(z[k][2] - tau[2], 0.f);
        o.w = fmaxf(z[k][3] - tau[3], 0.f);
        *reinterpret_cast<float4*>(out + row * COLS + col) = o;
    }
}

extern "C" void kernel_launch(void* const* d_in, const int* in_sizes, int n_in,
                              void* d_out, int out_size, void* d_ws, size_t ws_size,
                              hipStream_t stream) {
    const float* x = (const float*)d_in[0];
    const float* a = (const float*)d_in[1];
    float* out = (float*)d_out;
    hipLaunchKernelGGL(sparsemax_cols, dim3(COLS / CPB), dim3(TPB), 0, stream,
                       x, a, out);
}

// Round 2
// 264.507 us; speedup vs baseline: 1.1017x; 1.0786x over previous
//
#include <hip/hip_runtime.h>
#include <math.h>

// Sparsemax along axis 0 of z = -exp(a)*x, x: (4096, 8192) f32 row-major.
//
// R5: 3-kernel restructure attacking latency/issue-boundness.
// R4 post-mortem: pin didn't change VGPR_Count (64) or dur (~125us) =>
// remat/L3-re-read was NOT the bottleneck. Counters (VALU 5%, HBM 26%,
// Occ 32%) say latency-bound: (a) each wave load = 16 scattered 64B
// segments (rows 32KB apart) saturating miss-tracking slots; (b) 2
// phase-locked 1024-thread blocks/CU leave the memory pipe idle behind
// barriers.
//
// Key algebra: support requires z > colmax-1 (z_max - tau <= 1). For any
// row-chunk, chunkmax <= colmax, so filtering z > chunkmax-1 inside each
// chunk collects a SUPERSET of the true support. Michelot on a superset
// converges to the exact tau. So no global-max pass is needed:
//   K1: 32col x 512row blocks, 128B-line wave segments, chunk max +
//       candidate gather into per-column lists in d_ws (CAP=64/col,
//       expected ~25/col for this data).
//   K2: one wave/column Michelot on the tiny list; exact full-column
//       fallback if a list overflowed (correctness never depends on the
//       statistical bound).
//   K3: contiguous streaming epilogue out = max(s*x - tau[col], 0);
//       x is L3-hot from K1.
//
// ws layout: [0,32K) cnt int[8192]; [32K,64K) tau f32[8192];
//            [64K, 64K+2M) cand f32[8192][64].  (needs ~2.2 MiB)

constexpr int ROWS = 4096;
constexpr int COLS = 8192;
constexpr int CAP  = 64;

constexpr int CB = 32;          // cols per K1 block (128 B row segment)
constexpr int RB = 512;         // rows per K1 block
constexpr int T1 = 512;
constexpr int KK = RB / 64;     // 8 float4 loads per thread

// ---------------- K1: chunk max + candidate gather ----------------
__global__ __launch_bounds__(T1, 4)
void k1_gather(const float* __restrict__ x, const float* __restrict__ a,
               int* __restrict__ cnt, float* __restrict__ cand)
{
    __shared__ float wmax[8][33];   // per-wave col maxima (pad vs bank conflict)
    __shared__ float mcol[CB];      // chunk col maxima

    const int tid  = threadIdx.x;
    const int cq   = tid & 7;       // 8 lanes x 16B = one 128B row segment
    const int rg   = tid >> 3;      // [0,64) row group
    const int lane = tid & 63;
    const int wave = tid >> 6;

    const int  colb = blockIdx.x * CB;
    const long col  = colb + cq * 4;
    const int  row0 = blockIdx.y * RB;
    const float s   = -expf(a[0]);

    // load 8 rows x 4 cols per thread; wave instr = 8 x 128B full lines
    float z[KK][4];
#pragma unroll
    for (int k = 0; k < KK; ++k) {
        const long row = row0 + rg + k * 64;
        const float4 v = *reinterpret_cast<const float4*>(x + row * COLS + col);
        z[k][0] = s * v.x; z[k][1] = s * v.y;
        z[k][2] = s * v.z; z[k][3] = s * v.w;
    }
    // keep z resident (32 f32/thread fits the 64-VGPR budget)
#pragma unroll
    for (int k = 0; k < KK; ++k)
        asm volatile("" : "+v"(z[k][0]), "+v"(z[k][1]),
                          "+v"(z[k][2]), "+v"(z[k][3]));

    // per-column chunk max: thread -> wave butterfly (cq-preserving) -> LDS
    float pm[4] = {z[0][0], z[0][1], z[0][2], z[0][3]};
#pragma unroll
    for (int k = 1; k < KK; ++k)
#pragma unroll
        for (int c = 0; c < 4; ++c) pm[c] = fmaxf(pm[c], z[k][c]);
#pragma unroll
    for (int m = 8; m < 64; m <<= 1)
#pragma unroll
        for (int c = 0; c < 4; ++c) pm[c] = fmaxf(pm[c], __shfl_xor(pm[c], m, 64));
    if (lane < 8) {
#pragma unroll
        for (int c = 0; c < 4; ++c) wmax[wave][lane * 4 + c] = pm[c];
    }
    __syncthreads();
    if (tid < CB) {
        float m = wmax[0][tid];
#pragma unroll
        for (int w = 1; w < 8; ++w) m = fmaxf(m, wmax[w][tid]);
        mcol[tid] = m;
    }
    __syncthreads();

    // filter from registers: z > chunkmax - 1  (superset of true support)
    float thr[4];
#pragma unroll
    for (int c = 0; c < 4; ++c) thr[c] = mcol[cq * 4 + c] - 1.0f;
#pragma unroll
    for (int k = 0; k < KK; ++k)
#pragma unroll
        for (int c = 0; c < 4; ++c) {
            const float v = z[k][c];
            if (v > thr[c]) {
                const int ci  = colb + cq * 4 + c;
                const int idx = atomicAdd(&cnt[ci], 1);
                if (idx < CAP) cand[(long)ci * CAP + idx] = v;
            }
        }
}

// ---------------- K2: one wave per column, Michelot ----------------
__global__ __launch_bounds__(256)
void k2_solve(const int* __restrict__ cnt, const float* __restrict__ cand,
              const float* __restrict__ x, const float* __restrict__ a,
              float* __restrict__ tau)
{
    const int lane = threadIdx.x & 63;
    const int wave = threadIdx.x >> 6;
    const int col  = blockIdx.x * 4 + wave;
    const int K    = cnt[col];

    float t = -3.0e38f;
    if (K <= CAP) {
        // exact Michelot on the candidate list (superset of support)
        const float v = (lane < K) ? cand[(long)col * CAP + lane] : -3.3e38f;
        float prev = 0.f;
        for (int it = 0; it < CAP + 2; ++it) {
            const bool act = v > t;
            float ssum = act ? v : 0.f;
            float scnt = act ? 1.f : 0.f;
#pragma unroll
            for (int m = 1; m < 64; m <<= 1) {
                ssum += __shfl_xor(ssum, m, 64);
                scnt += __shfl_xor(scnt, m, 64);
            }
            t = (ssum - 1.0f) / scnt;       // scnt >= 1 (chunk maxima present)
            if (scnt == prev) break;
            prev = scnt;
        }
    } else {
        // overflow fallback: exact Michelot over the full column (L3-hot)
        const float s = -expf(a[0]);
        float prev = 0.f;
        for (int it = 0; it < 256; ++it) {
            float ssum = 0.f, scnt = 0.f;
            for (int i = 0; i < ROWS / 64; ++i) {
                const float zz = s * x[(long)(lane + i * 64) * COLS + col];
                if (zz > t) { ssum += zz; scnt += 1.f; }
            }
#pragma unroll
            for (int m = 1; m < 64; m <<= 1) {
                ssum += __shfl_xor(ssum, m, 64);
                scnt += __shfl_xor(scnt, m, 64);
            }
            t = (ssum - 1.0f) / scnt;
            if (scnt == prev) break;
            prev = scnt;
        }
    }
    if (lane == 0) tau[col] = t;
}

// ---------------- K3: streaming epilogue ----------------
__global__ __launch_bounds__(256, 8)
void k3_epilogue(const float* __restrict__ x, const float* __restrict__ a,
                 const float* __restrict__ tau, float* __restrict__ out)
{
    const float s = -expf(a[0]);
    const float4* x4 = reinterpret_cast<const float4*>(x);
    const float4* t4 = reinterpret_cast<const float4*>(tau);
    float4*       o4 = reinterpret_cast<float4*>(out);
    const int N4 = ROWS * (COLS / 4);
    const int stride = gridDim.x * blockDim.x;
    for (int i = blockIdx.x * blockDim.x + threadIdx.x; i < N4; i += stride) {
        const float4 v  = x4[i];
        const float4 tt = t4[i & (COLS / 4 - 1)];
        float4 o;
        o.x = fmaxf(fmaf(s, v.x, -tt.x), 0.f);
        o.y = fmaxf(fmaf(s, v.y, -tt.y), 0.f);
        o.z = fmaxf(fmaf(s, v.z, -tt.z), 0.f);
        o.w = fmaxf(fmaf(s, v.w, -tt.w), 0.f);
        o4[i] = o;
    }
}

extern "C" void kernel_launch(void* const* d_in, const int* in_sizes, int n_in,
                              void* d_out, int out_size, void* d_ws, size_t ws_size,
                              hipStream_t stream) {
    const float* x = (const float*)d_in[0];
    const float* a = (const float*)d_in[1];
    float* out = (float*)d_out;

    char*  ws   = (char*)d_ws;
    int*   cnt  = (int*)ws;                       // 32 KB
    float* tau  = (float*)(ws + 32 * 1024);       // 32 KB
    float* cand = (float*)(ws + 64 * 1024);       // 2 MiB

    hipMemsetAsync(cnt, 0, COLS * sizeof(int), stream);
    hipLaunchKernelGGL(k1_gather, dim3(COLS / CB, ROWS / RB), dim3(T1), 0, stream,
                       x, a, cnt, cand);
    hipLaunchKernelGGL(k2_solve, dim3(COLS / 4), dim3(256), 0, stream,
                       cnt, cand, x, a, tau);
    hipLaunchKernelGGL(k3_epilogue, dim3(2048), dim3(256), 0, stream,
                       x, a, tau, out);
}